// Round 9
// baseline (363.347 us; speedup 1.0000x reference)
//
#include <hip/hip_runtime.h>
#include <hip/hip_bf16.h>

typedef unsigned short u16;
typedef unsigned int u32;
typedef short short8 __attribute__((ext_vector_type(8)));
typedef float fx4 __attribute__((ext_vector_type(4)));
typedef u32 ux4 __attribute__((ext_vector_type(4)));
typedef u32 ux2 __attribute__((ext_vector_type(2)));

__device__ __forceinline__ float b2f(u16 x) {
  return __uint_as_float(((u32)x) << 16);
}
__device__ __forceinline__ u16 f2b(float f) {
  u32 u = __float_as_uint(f);
  u += 0x7fffu + ((u >> 16) & 1u);  // RNE
  return (u16)(u >> 16);
}
// HW packed f32x2 -> bf16x2 (RNE). No builtin on gfx950; inline asm per T12.
__device__ __forceinline__ u32 cvtpk(float a, float b) {
  u32 r;
  asm("v_cvt_pk_bf16_f32 %0, %1, %2" : "=v"(r) : "v"(a), "v"(b));
  return r;
}

// Async global->LDS DMA, 16B per lane. LDS dest = wave-uniform base + lane*16.
__device__ __forceinline__ void load16(const u16* g, u16* l) {
  __builtin_amdgcn_global_load_lds(
      (__attribute__((address_space(1))) void*)(u16*)g,
      (__attribute__((address_space(3))) void*)l, 16, 0, 0);
}

// ---------------------------------------------------------------------------
// f32 -> bf16 elementwise. grid = n/1024, block 256 (4 elems/thread).
// ---------------------------------------------------------------------------
__global__ __launch_bounds__(256) void cvt_f2b_kernel(
    const float* __restrict__ in, u16* __restrict__ out)
{
  int i = (blockIdx.x * 256 + threadIdx.x) * 4;
  fx4 v = *(const fx4*)(in + i);
  u16 o4[4];
#pragma unroll
  for (int j = 0; j < 4; ++j) o4[j] = f2b(v[j]);
  *(uint2*)(out + i) = *(uint2*)o4;
}

// ---------------------------------------------------------------------------
// Fused transpose + f32->bf16: out[batch][c][r] = bf16(in[batch][r][c]).
// grid: (C/32, R/32, nbatch), block: (32,8). out batch stride = C * out_ld.
// ---------------------------------------------------------------------------
__global__ __launch_bounds__(256) void transpose_f2b_kernel(
    const float* __restrict__ in, u16* __restrict__ out,
    int R, int C, int out_ld)
{
  __shared__ __align__(16) u16 tile[32][33];
  int tx = threadIdx.x, ty = threadIdx.y;
  int c0 = blockIdx.x * 32, r0 = blockIdx.y * 32;
  const float* inb = in + (size_t)blockIdx.z * R * C;
  u16* outb = out + (size_t)blockIdx.z * C * out_ld;
#pragma unroll
  for (int i = 0; i < 4; ++i)
    tile[ty + i * 8][tx] = f2b(inb[(size_t)(r0 + ty + i * 8) * C + c0 + tx]);
  __syncthreads();
#pragma unroll
  for (int i = 0; i < 4; ++i)
    outb[(size_t)(c0 + ty + i * 8) * out_ld + r0 + tx] = tile[tx][ty + i * 8];
}

// ---------------------------------------------------------------------------
// bf16 strided transpose: out[c][r] = in[r*in_ld + c]. grid (C/32, R/32).
// ---------------------------------------------------------------------------
__global__ __launch_bounds__(256) void transpose_b2b_kernel(
    const u16* __restrict__ in, u16* __restrict__ out, int in_ld, int out_ld)
{
  __shared__ __align__(16) u16 tile[32][33];
  int tx = threadIdx.x, ty = threadIdx.y;
  int c0 = blockIdx.x * 32, r0 = blockIdx.y * 32;
#pragma unroll
  for (int i = 0; i < 4; ++i)
    tile[ty + i * 8][tx] = in[(size_t)(r0 + ty + i * 8) * in_ld + c0 + tx];
  __syncthreads();
#pragma unroll
  for (int i = 0; i < 4; ++i)
    out[(size_t)(c0 + ty + i * 8) * out_ld + r0 + tx] = tile[tx][ty + i * 8];
}

// ---------------------------------------------------------------------------
// C[M,N] = A[M,K] * BT[N,K]^T; bf16 in, fp32 acc. 128x128 tile, BK=32,
// 4 waves x 64x64. global_load_lds dbuf staging, 1 barrier/K-tile, XOR swizzle.
// flags: 1 = store bf16 (else fp32), 2 = add f32 bias[col], 4 = relu.
// Used for the large-grid GEMMs (QKV, FFN1) where occupancy is healthy.
// ---------------------------------------------------------------------------
__global__ __launch_bounds__(256, 2) void gemm_bt(
    const u16* __restrict__ A, const u16* __restrict__ BT,
    const float* __restrict__ bias, void* __restrict__ Cp,
    int M, int N, int K, int flags)
{
  __shared__ __align__(16) u16 As[2][4096];
  __shared__ __align__(16) u16 Bs[2][4096];
  int tid = threadIdx.x;
  int lane = tid & 63, wid = tid >> 6;
  int l15 = lane & 15, quad = lane >> 4;
  int wm = wid >> 1, wn = wid & 1;
  int m0 = blockIdx.y * 128, n0 = blockIdx.x * 128;

  int srow = wid * 16 + (lane >> 2);
  int sswz = (((lane >> 2) & 3) + ((lane >> 4) & 3)) & 3;
  int gch = (lane & 3) ^ sswz;
  const u16* gA = A + (size_t)(m0 + srow) * K + gch * 8;
  const u16* gB = BT + (size_t)(n0 + srow) * K + gch * 8;
  size_t gstep = (size_t)64 * K;
  u16* lA = &As[0][wid * 512];
  u16* lB = &Bs[0][wid * 512];

  int rswz = ((l15 & 3) + (l15 >> 2)) & 3;
  int rphys = ((quad ^ rswz) & 3) << 3;

  fx4 acc[4][4];
#pragma unroll
  for (int i = 0; i < 4; ++i)
#pragma unroll
    for (int j = 0; j < 4; ++j) acc[i][j] = fx4{0.f, 0.f, 0.f, 0.f};

  int nt = K >> 5;
  load16(gA,         lA);
  load16(gA + gstep, lA + 2048);
  load16(gB,         lB);
  load16(gB + gstep, lB + 2048);

  for (int kt = 0; kt < nt; ++kt) {
    __syncthreads();
    if (kt + 1 < nt) {
      int buf = (kt + 1) & 1;
      const u16* ga = gA + (kt + 1) * 32;
      const u16* gb = gB + (kt + 1) * 32;
      load16(ga,         lA + buf * 4096);
      load16(ga + gstep, lA + buf * 4096 + 2048);
      load16(gb,         lB + buf * 4096);
      load16(gb + gstep, lB + buf * 4096 + 2048);
    }
    const u16* Ab = As[kt & 1];
    const u16* Bb = Bs[kt & 1];
    short8 af[4], bf[4];
#pragma unroll
    for (int t = 0; t < 4; ++t)
      af[t] = *(const short8*)&Ab[(wm * 64 + t * 16 + l15) * 32 + rphys];
#pragma unroll
    for (int t = 0; t < 4; ++t)
      bf[t] = *(const short8*)&Bb[(wn * 64 + t * 16 + l15) * 32 + rphys];
#pragma unroll
    for (int tm = 0; tm < 4; ++tm)
#pragma unroll
      for (int tn = 0; tn < 4; ++tn)
        acc[tm][tn] = __builtin_amdgcn_mfma_f32_16x16x32_bf16(
            af[tm], bf[tn], acc[tm][tn], 0, 0, 0);
  }

  bool obf = flags & 1, hb = flags & 2, rl = flags & 4;
#pragma unroll
  for (int tn = 0; tn < 4; ++tn) {
    int col = n0 + wn * 64 + tn * 16 + l15;
    float bv = hb ? bias[col] : 0.0f;
#pragma unroll
    for (int tm = 0; tm < 4; ++tm) {
      int row = m0 + wm * 64 + tm * 16 + (quad << 2);
#pragma unroll
      for (int r = 0; r < 4; ++r) {
        float v = acc[tm][tn][r] + bv;
        if (rl) v = fmaxf(v, 0.0f);
        size_t idx = (size_t)(row + r) * N + col;
        if (obf) ((u16*)Cp)[idx] = f2b(v);
        else ((float*)Cp)[idx] = v;
      }
    }
  }
}

// ---------------------------------------------------------------------------
// BK=64 variant for the grid-limited split-K GEMMs (Wo-proj, FFN2).
// 128x128 tile, 64 KB LDS (2 blocks/CU = exactly the 512-block grid), 32 MFMA
// per barrier (2x gemm_bt) so the staged-load latency is covered and the
// barrier/vmcnt drain count halves. 8-chunk XOR swizzle:
//   staging: LDS[row][c] = src[(c ^ (row&7))*8 ..], per-thread constant
//   read:    chunk = ((s<<2)|quad) ^ (l15&7)  (s = k-substep 0/1)
// Split-K over blockIdx.z into partial buffers at Cp + z*M*N (f32), with
// the bijective XCD-chunked swizzle when gridDim.z > 1.
// ---------------------------------------------------------------------------
__global__ __launch_bounds__(256, 2) void gemm_bt_k64(
    const u16* __restrict__ A, const u16* __restrict__ BT,
    const float* __restrict__ bias, void* __restrict__ Cp,
    int M, int N, int K, int flags)
{
  __shared__ __align__(16) u16 As[2][8192];
  __shared__ __align__(16) u16 Bs[2][8192];
  int tid = threadIdx.x;
  int lane = tid & 63, wid = tid >> 6;
  int l15 = lane & 15, quad = lane >> 4;
  int wm = wid >> 1, wn = wid & 1;

  int bx = blockIdx.x, by = blockIdx.y, bz = blockIdx.z;
  if (gridDim.z > 1) {
    int nx = gridDim.x, ny = gridDim.y;
    int total = nx * ny * (int)gridDim.z;
    int cpx = total >> 3;
    int lin = bx + nx * (by + ny * bz);
    int swb = (lin & 7) * cpx + (lin >> 3);
    bx = swb % nx;
    int t2 = swb / nx;
    by = t2 % ny;
    bz = t2 / ny;
  }
  int m0 = by * 128, n0 = bx * 128;
  int kc = K / (int)gridDim.z;  // multiple of 64

  // staging: wave covers 8 rows/load16; 4 sub-loads span 128 rows (+32 each)
  int r8 = lane >> 3;           // row & 7
  int clog = (lane & 7) ^ r8;   // source chunk for phys chunk lane&7
  const u16* gA = A + (size_t)(m0 + wid * 8 + r8) * K + bz * kc + clog * 8;
  const u16* gB = BT + (size_t)(n0 + wid * 8 + r8) * K + bz * kc + clog * 8;
  size_t gstep = (size_t)32 * K;
  u16* lA = &As[0][wid * 512];
  u16* lB = &Bs[0][wid * 512];

  fx4 acc[4][4];
#pragma unroll
  for (int i = 0; i < 4; ++i)
#pragma unroll
    for (int j = 0; j < 4; ++j) acc[i][j] = fx4{0.f, 0.f, 0.f, 0.f};

  int nt = kc >> 6;
#pragma unroll
  for (int i = 0; i < 4; ++i) {
    load16(gA + i * gstep, lA + i * 2048);
    load16(gB + i * gstep, lB + i * 2048);
  }

  for (int kt = 0; kt < nt; ++kt) {
    __syncthreads();
    if (kt + 1 < nt) {
      int buf = (kt + 1) & 1;
      const u16* ga = gA + (kt + 1) * 64;
      const u16* gb = gB + (kt + 1) * 64;
#pragma unroll
      for (int i = 0; i < 4; ++i) {
        load16(ga + i * gstep, lA + buf * 8192 + i * 2048);
        load16(gb + i * gstep, lB + buf * 8192 + i * 2048);
      }
    }
    const u16* Ab = As[kt & 1];
    const u16* Bb = Bs[kt & 1];
#pragma unroll
    for (int s = 0; s < 2; ++s) {
      int ch = (((s << 2) | quad) ^ (l15 & 7)) << 3;
      short8 af[4], bf[4];
#pragma unroll
      for (int t = 0; t < 4; ++t)
        af[t] = *(const short8*)&Ab[(wm * 64 + t * 16 + l15) * 64 + ch];
#pragma unroll
      for (int t = 0; t < 4; ++t)
        bf[t] = *(const short8*)&Bb[(wn * 64 + t * 16 + l15) * 64 + ch];
#pragma unroll
      for (int tm = 0; tm < 4; ++tm)
#pragma unroll
        for (int tn = 0; tn < 4; ++tn)
          acc[tm][tn] = __builtin_amdgcn_mfma_f32_16x16x32_bf16(
              af[tm], bf[tn], acc[tm][tn], 0, 0, 0);
    }
  }

  bool obf = flags & 1, hb = flags & 2, rl = flags & 4;
  u16* cb16 = (u16*)Cp + (size_t)bz * M * N;
  float* cf32 = (float*)Cp + (size_t)bz * M * N;
#pragma unroll
  for (int tn = 0; tn < 4; ++tn) {
    int col = n0 + wn * 64 + tn * 16 + l15;
    float bv = hb ? bias[col] : 0.0f;
#pragma unroll
    for (int tm = 0; tm < 4; ++tm) {
      int row = m0 + wm * 64 + tm * 16 + (quad << 2);
#pragma unroll
      for (int r = 0; r < 4; ++r) {
        float v = acc[tm][tn][r] + bv;
        if (rl) v = fmaxf(v, 0.0f);
        size_t idx = (size_t)(row + r) * N + col;
        if (obf) cb16[idx] = f2b(v);
        else cf32[idx] = v;
      }
    }
  }
}

// ---------------------------------------------------------------------------
// Flash attention, split-KV (no-max softmax => O and denom are LINEAR in key
// tiles, so KV-halves are independent partials). 32 queries per wave.
// grid: (S/128, H, B*2); z = b*2 + half; each block does 16 key-tiles.
// Writes UNNORMALIZED f32 partial O to po[half][4096][1024] and per-row
// partial sums to ps[row][h][half]. attn_combine_kernel finishes.
// QK^T swapped (mfma(K,Q)) with uniform key-row permutation sig; P goes to
// PV A-fragments via cvtpk + permlane32_swap (see round-5 notes).
// ---------------------------------------------------------------------------
__global__ __launch_bounds__(256, 2) void attn_kernel(
    const u16* __restrict__ qkv, const u16* __restrict__ vT,
    float* __restrict__ po, float* __restrict__ ps)
{
  __shared__ __align__(16) u16 Ks[2][4096];
  __shared__ __align__(16) u16 Vs[2][4096];
  int tid = threadIdx.x;
  int lane = tid & 63, wid = tid >> 6;
  int l15 = lane & 15, quad = lane >> 4;
  int bz = blockIdx.z;
  int b = bz >> 1, half = bz & 1;
  int h = blockIdx.y;
  int q0 = blockIdx.x * 128 + wid * 32;
  int k0 = half * 1024;  // key offset of this half

  const u16* qbA = qkv + (size_t)(b * 2048 + q0 + l15) * 3072 + h * 64 + (quad << 3);
  short8 qA0 = *(const short8*)qbA;
  short8 qA1 = *(const short8*)(qbA + 32);
  const u16* qbB = qbA + (size_t)16 * 3072;
  short8 qB0 = *(const short8*)qbB;
  short8 qB1 = *(const short8*)(qbB + 32);

  // staging (K and V): 16B/lane, XOR-swizzled source columns
  int srow = tid >> 3;
  int gc8 = ((tid & 7) ^ (srow & 7)) << 3;
  const u16* kg = qkv + (size_t)(b * 2048 + k0 + srow) * 3072 + 1024 + h * 64 + gc8;
  const u16* vg = vT + (size_t)(h * 64 + srow) * 4096 + b * 2048 + k0 + gc8;
  u16* lk = &Ks[0][wid * 512];
  u16* lv = &Vs[0][wid * 512];

  // uniform K A-operand row permutation sig (same for all subs)
  int lq = l15 >> 2;
  int rs = ((((lq & 1) << 1) | (lq >> 1)) << 2) | (l15 & 3);
  int sk = rs & 7;

  fx4 oaccA[4], oaccB[4];
  float sumA = 0.0f, sumB = 0.0f;
#pragma unroll
  for (int i = 0; i < 4; ++i) {
    oaccA[i] = fx4{0.f, 0.f, 0.f, 0.f};
    oaccB[i] = fx4{0.f, 0.f, 0.f, 0.f};
  }

  load16(kg,             lk);
  load16(kg + 32 * 3072, lk + 2048);
  load16(vg,             lv);
  load16(vg + 32 * 4096, lv + 2048);

  int swz = l15 & 7;
  const float SC = 0.18033688011112042f;  // (1/8) * log2(e)
  for (int kt = 0; kt < 16; ++kt) {
    __syncthreads();
    if (kt + 1 < 16) {
      int buf = (kt + 1) & 1;
      const u16* kgn = kg + (size_t)(kt + 1) * 64 * 3072;
      const u16* vgn = vg + (kt + 1) * 64;
      load16(kgn,             lk + buf * 4096);
      load16(kgn + 32 * 3072, lk + buf * 4096 + 2048);
      load16(vgn,             lv + buf * 4096);
      load16(vgn + 32 * 4096, lv + buf * 4096 + 2048);
    }
    const u16* Kb = Ks[kt & 1];
    const u16* Vb = Vs[kt & 1];

    // QK^T swapped, K fragment shared by both q-groups
    fx4 scA[4], scB[4];
    __builtin_amdgcn_s_setprio(1);
#pragma unroll
    for (int sub = 0; sub < 4; ++sub) {
      const u16* rp = &Kb[(sub * 16 + rs) * 64];
      short8 kf0 = *(const short8*)&rp[((quad ^ sk) & 7) << 3];
      short8 kf1 = *(const short8*)&rp[(((4 | quad) ^ sk) & 7) << 3];
      scA[sub] = fx4{0.f, 0.f, 0.f, 0.f};
      scA[sub] = __builtin_amdgcn_mfma_f32_16x16x32_bf16(kf0, qA0, scA[sub], 0, 0, 0);
      scA[sub] = __builtin_amdgcn_mfma_f32_16x16x32_bf16(kf1, qA1, scA[sub], 0, 0, 0);
      scB[sub] = fx4{0.f, 0.f, 0.f, 0.f};
      scB[sub] = __builtin_amdgcn_mfma_f32_16x16x32_bf16(kf0, qB0, scB[sub], 0, 0, 0);
      scB[sub] = __builtin_amdgcn_mfma_f32_16x16x32_bf16(kf1, qB1, scB[sub], 0, 0, 0);
    }
    __builtin_amdgcn_s_setprio(0);

    // softmax numerators in-register (exp2 with folded scale)
    u32 WA[4][2], WB[4][2];
    float psA = 0.0f, psB = 0.0f;
#pragma unroll
    for (int sub = 0; sub < 4; ++sub) {
      float a0 = __builtin_amdgcn_exp2f(scA[sub][0] * SC);
      float a1 = __builtin_amdgcn_exp2f(scA[sub][1] * SC);
      float a2 = __builtin_amdgcn_exp2f(scA[sub][2] * SC);
      float a3 = __builtin_amdgcn_exp2f(scA[sub][3] * SC);
      psA += (a0 + a1) + (a2 + a3);
      WA[sub][0] = cvtpk(a0, a1);
      WA[sub][1] = cvtpk(a2, a3);
      float b0 = __builtin_amdgcn_exp2f(scB[sub][0] * SC);
      float b1 = __builtin_amdgcn_exp2f(scB[sub][1] * SC);
      float b2 = __builtin_amdgcn_exp2f(scB[sub][2] * SC);
      float b3 = __builtin_amdgcn_exp2f(scB[sub][3] * SC);
      psB += (b0 + b1) + (b2 + b3);
      WB[sub][0] = cvtpk(b0, b1);
      WB[sub][1] = cvtpk(b2, b3);
    }
    sumA += psA;
    sumB += psB;

    // exchange with quad q^2 partner (lanes l <-> l^32); uniform slot map
    ux2 eA00 = __builtin_amdgcn_permlane32_swap(WA[0][0], WA[1][0], false, false);
    ux2 eA01 = __builtin_amdgcn_permlane32_swap(WA[0][1], WA[1][1], false, false);
    ux2 eA10 = __builtin_amdgcn_permlane32_swap(WA[2][0], WA[3][0], false, false);
    ux2 eA11 = __builtin_amdgcn_permlane32_swap(WA[2][1], WA[3][1], false, false);
    short8 pa1A = __builtin_bit_cast(short8, ux4{eA00[0], eA01[0], eA00[1], eA01[1]});
    short8 pa2A = __builtin_bit_cast(short8, ux4{eA10[0], eA11[0], eA10[1], eA11[1]});
    ux2 eB00 = __builtin_amdgcn_permlane32_swap(WB[0][0], WB[1][0], false, false);
    ux2 eB01 = __builtin_amdgcn_permlane32_swap(WB[0][1], WB[1][1], false, false);
    ux2 eB10 = __builtin_amdgcn_permlane32_swap(WB[2][0], WB[3][0], false, false);
    ux2 eB11 = __builtin_amdgcn_permlane32_swap(WB[2][1], WB[3][1], false, false);
    short8 pa1B = __builtin_bit_cast(short8, ux4{eB00[0], eB01[0], eB00[1], eB01[1]});
    short8 pa2B = __builtin_bit_cast(short8, ux4{eB10[0], eB11[0], eB10[1], eB11[1]});

    // PV: V fragment shared by both q-groups (plain b128, conflict-free)
    __builtin_amdgcn_s_setprio(1);
#pragma unroll
    for (int dt = 0; dt < 4; ++dt) {
      const u16* rp = &Vb[(dt * 16 + l15) * 64];
      short8 vf0 = *(const short8*)&rp[((quad ^ swz) & 7) << 3];
      short8 vf1 = *(const short8*)&rp[(((4 | quad) ^ swz) & 7) << 3];
      oaccA[dt] = __builtin_amdgcn_mfma_f32_16x16x32_bf16(pa1A, vf0, oaccA[dt], 0, 0, 0);
      oaccA[dt] = __builtin_amdgcn_mfma_f32_16x16x32_bf16(pa2A, vf1, oaccA[dt], 0, 0, 0);
      oaccB[dt] = __builtin_amdgcn_mfma_f32_16x16x32_bf16(pa1B, vf0, oaccB[dt], 0, 0, 0);
      oaccB[dt] = __builtin_amdgcn_mfma_f32_16x16x32_bf16(pa2B, vf1, oaccB[dt], 0, 0, 0);
    }
    __builtin_amdgcn_s_setprio(0);
  }
  // partial denominators: reduce the 4 quads sharing each l15
  sumA += __shfl_xor(sumA, 16, 64);
  sumA += __shfl_xor(sumA, 32, 64);
  sumB += __shfl_xor(sumB, 16, 64);
  sumB += __shfl_xor(sumB, 32, 64);
  if (lane < 16) {
    size_t rowA = (size_t)(b * 2048 + q0 + lane);
    ps[(rowA * 16 + h) * 2 + half] = sumA;
    ps[((rowA + 16) * 16 + h) * 2 + half] = sumB;
  }
  // unnormalized partial O (f32)
  float* pob = po + (size_t)half * 4194304;
#pragma unroll
  for (int dt = 0; dt < 4; ++dt) {
    int col = h * 64 + dt * 16 + l15;
#pragma unroll
    for (int r = 0; r < 4; ++r) {
      size_t rowA = (size_t)(b * 2048 + q0 + (quad << 2) + r);
      pob[rowA * 1024 + col] = oaccA[dt][r];
      pob[(rowA + 16) * 1024 + col] = oaccB[dt][r];
    }
  }
}

// ---------------------------------------------------------------------------
// Combine split-KV partials: o = bf16((po0 + po1) * 1/(ps0 + ps1)).
// grid 4096 (one row/block), block 256 (4 cols/thread).
// ---------------------------------------------------------------------------
__global__ __launch_bounds__(256) void attn_combine_kernel(
    const float* __restrict__ po, const float* __restrict__ ps,
    u16* __restrict__ o)
{
  int row = blockIdx.x, tid = threadIdx.x;
  size_t base = (size_t)row * 1024 + tid * 4;
  fx4 a = *(const fx4*)(po + base);
  fx4 c = *(const fx4*)(po + 4194304 + base);
  int h = (tid * 4) >> 6;
  const float* pr = ps + ((size_t)row * 16 + h) * 2;
  float inv = 1.0f / (pr[0] + pr[1]);
  u16 o4[4];
#pragma unroll
  for (int i = 0; i < 4; ++i) o4[i] = f2b((a[i] + c[i]) * inv);
  *(uint2*)(o + base) = *(uint2*)o4;
}

// ---------------------------------------------------------------------------
// LN: LayerNorm(main0 + main1 + res + cbias[col]) * g + beta, row len 1024.
// main1 is the second split-K partial (always present); cbias nullable
// (folds the FFN2 column bias in, since the GEMM now emits raw partials).
// ---------------------------------------------------------------------------
__global__ __launch_bounds__(256) void ln_kernel(
    const float* __restrict__ main0, const float* __restrict__ main1,
    const float* __restrict__ res, const float* __restrict__ cbias,
    const float* __restrict__ g, const float* __restrict__ beta,
    u16* __restrict__ out_b, float* __restrict__ out_f)
{
  __shared__ float red[8];
  int row = blockIdx.x, tid = threadIdx.x;
  size_t base = (size_t)row * 1024 + tid * 4;
  fx4 v = *(const fx4*)(main0 + base);
  fx4 v1 = *(const fx4*)(main1 + base);
  fx4 rv = *(const fx4*)(res + base);
#pragma unroll
  for (int i = 0; i < 4; ++i) v[i] += v1[i] + rv[i];
  if (cbias) {
    fx4 cb = *(const fx4*)(cbias + tid * 4);
#pragma unroll
    for (int i = 0; i < 4; ++i) v[i] += cb[i];
  }
  float s = v[0] + v[1] + v[2] + v[3];
  float sq = v[0] * v[0] + v[1] * v[1] + v[2] * v[2] + v[3] * v[3];
#pragma unroll
  for (int off = 32; off >= 1; off >>= 1) {
    s += __shfl_xor(s, off, 64);
    sq += __shfl_xor(sq, off, 64);
  }
  int wid = tid >> 6, lane = tid & 63;
  if (lane == 0) { red[wid] = s; red[wid + 4] = sq; }
  __syncthreads();
  float S = red[0] + red[1] + red[2] + red[3];
  float SQ = red[4] + red[5] + red[6] + red[7];
  float mean = S * (1.0f / 1024.0f);
  float var = SQ * (1.0f / 1024.0f) - mean * mean;
  float rs = rsqrtf(var + 1e-5f);
  fx4 gv = *(const fx4*)(g + tid * 4);
  fx4 bv = *(const fx4*)(beta + tid * 4);
  float of[4];
#pragma unroll
  for (int i = 0; i < 4; ++i) of[i] = (v[i] - mean) * rs * gv[i] + bv[i];
  if (out_f) *(fx4*)(out_f + base) = *(const fx4*)of;
  if (out_b) {
    u16 o4[4];
#pragma unroll
    for (int i = 0; i < 4; ++i) o4[i] = f2b(of[i]);
    *(uint2*)(out_b + base) = *(uint2*)o4;
  }
}

// ---------------------------------------------------------------------------
// Workspace (peak 88 MiB, liveness-checked):
//   xb    bf16 [ 0, 8)M   (dead after QKV gemm)
//   wqkvT bf16 [ 8,14)M   (dead after QKV gemm)
//   woT   bf16 [38,40)M   (dead after Wo-proj)
//   qkv   bf16 [40,64)M   (dead after attn)
//   vT    bf16 [64,72)M   (dead after attn)
//   po    f32  [ 0,32)M   attn split-KV partials (dead after combine)
//   ps    f32  [32,33)M   attn partial sums      (dead after combine)
//   ob    bf16 [72,80)M   (dead after Wo-proj)
//   aout  f32  [ 0,32)M   2 split-K partials (dead after LN1)
//   x1f   f32  [40,56)M   (live until LN2)
//   x1    bf16 [64,72)M   (dead after FFN1)
//   w1T   bf16 [56,64)M   (dead after FFN1)
//   w2T   bf16 [ 0, 8)M   (live until FFN2)
//   hbuf  bf16 [ 8,40)M   (live until FFN2)
//   ffn   f32  [56,88)M   2 split-K partials (live until LN2)
// ---------------------------------------------------------------------------
extern "C" void kernel_launch(void* const* d_in, const int* in_sizes, int n_in,
                              void* d_out, int out_size, void* d_ws, size_t ws_size,
                              hipStream_t stream) {
  (void)in_sizes; (void)n_in; (void)out_size; (void)ws_size;
  const float* x     = (const float*)d_in[0];
  const float* Wq    = (const float*)d_in[1];
  const float* Wk    = (const float*)d_in[2];
  const float* Wv    = (const float*)d_in[3];
  const float* Wo    = (const float*)d_in[4];
  const float* g1    = (const float*)d_in[5];
  const float* bb1   = (const float*)d_in[6];
  const float* W1    = (const float*)d_in[7];
  const float* bias1 = (const float*)d_in[8];
  const float* W2    = (const float*)d_in[9];
  const float* bias2 = (const float*)d_in[10];
  const float* g2    = (const float*)d_in[11];
  const float* bb2   = (const float*)d_in[12];

  char* ws = (char*)d_ws;
  const size_t MB = 1048576;
  u16* xb     = (u16*)(ws);
  u16* wqkvT  = (u16*)(ws + 8 * MB);
  u16* woT    = (u16*)(ws + 38 * MB);
  u16* qkv    = (u16*)(ws + 40 * MB);
  u16* vT     = (u16*)(ws + 64 * MB);
  u16* ob     = (u16*)(ws + 72 * MB);
  float* po   = (float*)(ws);            // 2 x 16MB attn partials
  float* ps   = (float*)(ws + 32 * MB);  // 512 KB partial sums
  float* aout = (float*)(ws);            // 2 partials, 16MB each
  u16* x1     = (u16*)(ws + 64 * MB);
  float* x1f  = (float*)(ws + 40 * MB);
  u16* w1T    = (u16*)(ws + 56 * MB);
  u16* w2T    = (u16*)(ws);
  u16* hbuf   = (u16*)(ws + 8 * MB);
  float* ffn  = (float*)(ws + 56 * MB);  // 2 partials, 16MB each

  dim3 tb(32, 8, 1);
  cvt_f2b_kernel<<<4096, 256, 0, stream>>>(x, xb);
  transpose_f2b_kernel<<<dim3(2, 32, 16), tb, 0, stream>>>(Wq, wqkvT,           1024, 64, 1024);
  transpose_f2b_kernel<<<dim3(2, 32, 16), tb, 0, stream>>>(Wk, wqkvT + 1048576, 1024, 64, 1024);
  transpose_f2b_kernel<<<dim3(2, 32, 16), tb, 0, stream>>>(Wv, wqkvT + 2097152, 1024, 64, 1024);
  transpose_f2b_kernel<<<dim3(32, 32, 1), tb, 0, stream>>>(Wo, woT, 1024, 1024, 1024);

  // qkv = x @ [Wq|Wk|Wv]  (bf16 out)
  gemm_bt<<<dim3(24, 32), 256, 0, stream>>>(xb, wqkvT, nullptr, qkv, 4096, 3072, 1024, 1);
  // vT = (V slice of qkv)^T
  transpose_b2b_kernel<<<dim3(32, 128), tb, 0, stream>>>(qkv + 2048, vT, 3072, 4096);
  // attention, split-KV: partials -> po/ps; combine -> ob (bf16)
  attn_kernel<<<dim3(16, 16, 4), 256, 0, stream>>>(qkv, vT, po, ps);
  attn_combine_kernel<<<4096, 256, 0, stream>>>(po, ps, ob);
  // aout partials = ob @ Wo  (f32, split-K=2, BK=64, XCD-swizzled)
  gemm_bt_k64<<<dim3(8, 32, 2), 256, 0, stream>>>(ob, woT, nullptr, aout, 4096, 1024, 1024, 0);
  // x1 = LN(aout0 + aout1 + x): bf16 (FFN1 operand) + f32 (LN2 residual)
  ln_kernel<<<4096, 256, 0, stream>>>(aout, aout + 4194304, x, nullptr, g1, bb1, x1, x1f);
  // lazy weight transposes into dead regions
  transpose_f2b_kernel<<<dim3(128, 32, 1), tb, 0, stream>>>(W1, w1T, 1024, 4096, 1024);
  transpose_f2b_kernel<<<dim3(32, 128, 1), tb, 0, stream>>>(W2, w2T, 4096, 1024, 4096);
  // hbuf = relu(x1 @ W1 + b1)  (bf16 out)
  gemm_bt<<<dim3(32, 32), 256, 0, stream>>>(x1, w1T, bias1, hbuf, 4096, 4096, 1024, 1 | 2 | 4);
  // ffn partials = hbuf @ W2  (f32, split-K=2, BK=64, XCD-swizzled)
  gemm_bt_k64<<<dim3(8, 32, 2), 256, 0, stream>>>(hbuf, w2T, nullptr, ffn, 4096, 1024, 4096, 0);
  // out = LN(ffn0 + ffn1 + bias2 + x1f) -> f32 d_out
  ln_kernel<<<4096, 256, 0, stream>>>(ffn, ffn + 4194304, x1f, bias2, g2, bb2, nullptr, (float*)d_out);
}

// Round 10
// 357.675 us; speedup vs baseline: 1.0159x; 1.0159x over previous
//
#include <hip/hip_runtime.h>
#include <hip/hip_bf16.h>

typedef unsigned short u16;
typedef unsigned int u32;
typedef short short8 __attribute__((ext_vector_type(8)));
typedef float fx4 __attribute__((ext_vector_type(4)));
typedef u32 ux4 __attribute__((ext_vector_type(4)));
typedef u32 ux2 __attribute__((ext_vector_type(2)));

__device__ __forceinline__ float b2f(u16 x) {
  return __uint_as_float(((u32)x) << 16);
}
__device__ __forceinline__ u16 f2b(float f) {
  u32 u = __float_as_uint(f);
  u += 0x7fffu + ((u >> 16) & 1u);  // RNE
  return (u16)(u >> 16);
}
// HW packed f32x2 -> bf16x2 (RNE). No builtin on gfx950; inline asm per T12.
__device__ __forceinline__ u32 cvtpk(float a, float b) {
  u32 r;
  asm("v_cvt_pk_bf16_f32 %0, %1, %2" : "=v"(r) : "v"(a), "v"(b));
  return r;
}

// Async global->LDS DMA, 16B per lane. LDS dest = wave-uniform base + lane*16.
__device__ __forceinline__ void load16(const u16* g, u16* l) {
  __builtin_amdgcn_global_load_lds(
      (__attribute__((address_space(1))) void*)(u16*)g,
      (__attribute__((address_space(3))) void*)l, 16, 0, 0);
}

// ---------------------------------------------------------------------------
// f32 -> bf16 elementwise. grid = n/1024, block 256 (4 elems/thread).
// ---------------------------------------------------------------------------
__global__ __launch_bounds__(256) void cvt_f2b_kernel(
    const float* __restrict__ in, u16* __restrict__ out)
{
  int i = (blockIdx.x * 256 + threadIdx.x) * 4;
  fx4 v = *(const fx4*)(in + i);
  u16 o4[4];
#pragma unroll
  for (int j = 0; j < 4; ++j) o4[j] = f2b(v[j]);
  *(uint2*)(out + i) = *(uint2*)o4;
}

// ---------------------------------------------------------------------------
// Fused transpose + f32->bf16: out[batch][c][r] = bf16(in[batch][r][c]).
// grid: (C/32, R/32, nbatch), block: (32,8). out batch stride = C * out_ld.
// ---------------------------------------------------------------------------
__global__ __launch_bounds__(256) void transpose_f2b_kernel(
    const float* __restrict__ in, u16* __restrict__ out,
    int R, int C, int out_ld)
{
  __shared__ __align__(16) u16 tile[32][33];
  int tx = threadIdx.x, ty = threadIdx.y;
  int c0 = blockIdx.x * 32, r0 = blockIdx.y * 32;
  const float* inb = in + (size_t)blockIdx.z * R * C;
  u16* outb = out + (size_t)blockIdx.z * C * out_ld;
#pragma unroll
  for (int i = 0; i < 4; ++i)
    tile[ty + i * 8][tx] = f2b(inb[(size_t)(r0 + ty + i * 8) * C + c0 + tx]);
  __syncthreads();
#pragma unroll
  for (int i = 0; i < 4; ++i)
    outb[(size_t)(c0 + ty + i * 8) * out_ld + r0 + tx] = tile[tx][ty + i * 8];
}

// ---------------------------------------------------------------------------
// bf16 strided transpose: out[c][r] = in[r*in_ld + c]. grid (C/32, R/32).
// ---------------------------------------------------------------------------
__global__ __launch_bounds__(256) void transpose_b2b_kernel(
    const u16* __restrict__ in, u16* __restrict__ out, int in_ld, int out_ld)
{
  __shared__ __align__(16) u16 tile[32][33];
  int tx = threadIdx.x, ty = threadIdx.y;
  int c0 = blockIdx.x * 32, r0 = blockIdx.y * 32;
#pragma unroll
  for (int i = 0; i < 4; ++i)
    tile[ty + i * 8][tx] = in[(size_t)(r0 + ty + i * 8) * in_ld + c0 + tx];
  __syncthreads();
#pragma unroll
  for (int i = 0; i < 4; ++i)
    out[(size_t)(c0 + ty + i * 8) * out_ld + r0 + tx] = tile[tx][ty + i * 8];
}

// ---------------------------------------------------------------------------
// C[M,N] = A[M,K] * BT[N,K]^T; bf16 in, fp32 acc. 128x128 tile, BK=32,
// 4 waves x 64x64. global_load_lds dbuf staging, 1 barrier/K-tile, XOR swizzle.
// flags: 1 = store bf16 (else fp32), 2 = add f32 bias[col], 4 = relu.
// Used for QKV (768-block grid where BK=64's 2-blocks/CU would leave a
// half-idle tail round).
// ---------------------------------------------------------------------------
__global__ __launch_bounds__(256, 2) void gemm_bt(
    const u16* __restrict__ A, const u16* __restrict__ BT,
    const float* __restrict__ bias, void* __restrict__ Cp,
    int M, int N, int K, int flags)
{
  __shared__ __align__(16) u16 As[2][4096];
  __shared__ __align__(16) u16 Bs[2][4096];
  int tid = threadIdx.x;
  int lane = tid & 63, wid = tid >> 6;
  int l15 = lane & 15, quad = lane >> 4;
  int wm = wid >> 1, wn = wid & 1;
  int m0 = blockIdx.y * 128, n0 = blockIdx.x * 128;

  int srow = wid * 16 + (lane >> 2);
  int sswz = (((lane >> 2) & 3) + ((lane >> 4) & 3)) & 3;
  int gch = (lane & 3) ^ sswz;
  const u16* gA = A + (size_t)(m0 + srow) * K + gch * 8;
  const u16* gB = BT + (size_t)(n0 + srow) * K + gch * 8;
  size_t gstep = (size_t)64 * K;
  u16* lA = &As[0][wid * 512];
  u16* lB = &Bs[0][wid * 512];

  int rswz = ((l15 & 3) + (l15 >> 2)) & 3;
  int rphys = ((quad ^ rswz) & 3) << 3;

  fx4 acc[4][4];
#pragma unroll
  for (int i = 0; i < 4; ++i)
#pragma unroll
    for (int j = 0; j < 4; ++j) acc[i][j] = fx4{0.f, 0.f, 0.f, 0.f};

  int nt = K >> 5;
  load16(gA,         lA);
  load16(gA + gstep, lA + 2048);
  load16(gB,         lB);
  load16(gB + gstep, lB + 2048);

  for (int kt = 0; kt < nt; ++kt) {
    __syncthreads();
    if (kt + 1 < nt) {
      int buf = (kt + 1) & 1;
      const u16* ga = gA + (kt + 1) * 32;
      const u16* gb = gB + (kt + 1) * 32;
      load16(ga,         lA + buf * 4096);
      load16(ga + gstep, lA + buf * 4096 + 2048);
      load16(gb,         lB + buf * 4096);
      load16(gb + gstep, lB + buf * 4096 + 2048);
    }
    const u16* Ab = As[kt & 1];
    const u16* Bb = Bs[kt & 1];
    short8 af[4], bf[4];
#pragma unroll
    for (int t = 0; t < 4; ++t)
      af[t] = *(const short8*)&Ab[(wm * 64 + t * 16 + l15) * 32 + rphys];
#pragma unroll
    for (int t = 0; t < 4; ++t)
      bf[t] = *(const short8*)&Bb[(wn * 64 + t * 16 + l15) * 32 + rphys];
#pragma unroll
    for (int tm = 0; tm < 4; ++tm)
#pragma unroll
      for (int tn = 0; tn < 4; ++tn)
        acc[tm][tn] = __builtin_amdgcn_mfma_f32_16x16x32_bf16(
            af[tm], bf[tn], acc[tm][tn], 0, 0, 0);
  }

  bool obf = flags & 1, hb = flags & 2, rl = flags & 4;
#pragma unroll
  for (int tn = 0; tn < 4; ++tn) {
    int col = n0 + wn * 64 + tn * 16 + l15;
    float bv = hb ? bias[col] : 0.0f;
#pragma unroll
    for (int tm = 0; tm < 4; ++tm) {
      int row = m0 + wm * 64 + tm * 16 + (quad << 2);
#pragma unroll
      for (int r = 0; r < 4; ++r) {
        float v = acc[tm][tn][r] + bv;
        if (rl) v = fmaxf(v, 0.0f);
        size_t idx = (size_t)(row + r) * N + col;
        if (obf) ((u16*)Cp)[idx] = f2b(v);
        else ((float*)Cp)[idx] = v;
      }
    }
  }
}

// ---------------------------------------------------------------------------
// BK=64 variant for the latency-limited GEMMs (Wo-proj, FFN1, FFN2).
// 128x128 tile, 64 KB LDS (2 blocks/CU), 32 MFMA per barrier (2x gemm_bt) so
// the staged-load latency is covered and the barrier/vmcnt drain count halves
// (measured: FFN2 left the top-5 after conversion, round 8). 8-chunk XOR:
//   staging: LDS[row][c] = src[(c ^ (row&7))*8 ..], per-thread constant
//   read:    chunk = ((s<<2)|quad) ^ (l15&7)  (s = k-substep 0/1)
// Optional split-K over blockIdx.z into partial f32 buffers at Cp + z*M*N,
// with the bijective XCD-chunked swizzle when gridDim.z > 1.
// flags as gemm_bt.
// ---------------------------------------------------------------------------
__global__ __launch_bounds__(256, 2) void gemm_bt_k64(
    const u16* __restrict__ A, const u16* __restrict__ BT,
    const float* __restrict__ bias, void* __restrict__ Cp,
    int M, int N, int K, int flags)
{
  __shared__ __align__(16) u16 As[2][8192];
  __shared__ __align__(16) u16 Bs[2][8192];
  int tid = threadIdx.x;
  int lane = tid & 63, wid = tid >> 6;
  int l15 = lane & 15, quad = lane >> 4;
  int wm = wid >> 1, wn = wid & 1;

  int bx = blockIdx.x, by = blockIdx.y, bz = blockIdx.z;
  if (gridDim.z > 1) {
    int nx = gridDim.x, ny = gridDim.y;
    int total = nx * ny * (int)gridDim.z;
    int cpx = total >> 3;
    int lin = bx + nx * (by + ny * bz);
    int swb = (lin & 7) * cpx + (lin >> 3);
    bx = swb % nx;
    int t2 = swb / nx;
    by = t2 % ny;
    bz = t2 / ny;
  }
  int m0 = by * 128, n0 = bx * 128;
  int kc = K / (int)gridDim.z;  // multiple of 64

  // staging: wave covers 8 rows/load16; 4 sub-loads span 128 rows (+32 each)
  int r8 = lane >> 3;           // row & 7
  int clog = (lane & 7) ^ r8;   // source chunk for phys chunk lane&7
  const u16* gA = A + (size_t)(m0 + wid * 8 + r8) * K + bz * kc + clog * 8;
  const u16* gB = BT + (size_t)(n0 + wid * 8 + r8) * K + bz * kc + clog * 8;
  size_t gstep = (size_t)32 * K;
  u16* lA = &As[0][wid * 512];
  u16* lB = &Bs[0][wid * 512];

  fx4 acc[4][4];
#pragma unroll
  for (int i = 0; i < 4; ++i)
#pragma unroll
    for (int j = 0; j < 4; ++j) acc[i][j] = fx4{0.f, 0.f, 0.f, 0.f};

  int nt = kc >> 6;
#pragma unroll
  for (int i = 0; i < 4; ++i) {
    load16(gA + i * gstep, lA + i * 2048);
    load16(gB + i * gstep, lB + i * 2048);
  }

  for (int kt = 0; kt < nt; ++kt) {
    __syncthreads();
    if (kt + 1 < nt) {
      int buf = (kt + 1) & 1;
      const u16* ga = gA + (kt + 1) * 64;
      const u16* gb = gB + (kt + 1) * 64;
#pragma unroll
      for (int i = 0; i < 4; ++i) {
        load16(ga + i * gstep, lA + buf * 8192 + i * 2048);
        load16(gb + i * gstep, lB + buf * 8192 + i * 2048);
      }
    }
    const u16* Ab = As[kt & 1];
    const u16* Bb = Bs[kt & 1];
#pragma unroll
    for (int s = 0; s < 2; ++s) {
      int ch = (((s << 2) | quad) ^ (l15 & 7)) << 3;
      short8 af[4], bf[4];
#pragma unroll
      for (int t = 0; t < 4; ++t)
        af[t] = *(const short8*)&Ab[(wm * 64 + t * 16 + l15) * 64 + ch];
#pragma unroll
      for (int t = 0; t < 4; ++t)
        bf[t] = *(const short8*)&Bb[(wn * 64 + t * 16 + l15) * 64 + ch];
#pragma unroll
      for (int tm = 0; tm < 4; ++tm)
#pragma unroll
        for (int tn = 0; tn < 4; ++tn)
          acc[tm][tn] = __builtin_amdgcn_mfma_f32_16x16x32_bf16(
              af[tm], bf[tn], acc[tm][tn], 0, 0, 0);
    }
  }

  bool obf = flags & 1, hb = flags & 2, rl = flags & 4;
  u16* cb16 = (u16*)Cp + (size_t)bz * M * N;
  float* cf32 = (float*)Cp + (size_t)bz * M * N;
#pragma unroll
  for (int tn = 0; tn < 4; ++tn) {
    int col = n0 + wn * 64 + tn * 16 + l15;
    float bv = hb ? bias[col] : 0.0f;
#pragma unroll
    for (int tm = 0; tm < 4; ++tm) {
      int row = m0 + wm * 64 + tm * 16 + (quad << 2);
#pragma unroll
      for (int r = 0; r < 4; ++r) {
        float v = acc[tm][tn][r] + bv;
        if (rl) v = fmaxf(v, 0.0f);
        size_t idx = (size_t)(row + r) * N + col;
        if (obf) cb16[idx] = f2b(v);
        else cf32[idx] = v;
      }
    }
  }
}

// ---------------------------------------------------------------------------
// Flash attention, split-KV (no-max softmax => O and denom are LINEAR in key
// tiles, so KV-halves are independent partials). 32 queries per wave.
// grid: (S/128, H, B*2); z = b*2 + half; each block does 16 key-tiles.
// Writes UNNORMALIZED f32 partial O to po[half][4096][1024] and per-row
// partial sums to ps[row][h][half]. attn_combine_kernel finishes.
// QK^T swapped (mfma(K,Q)) with uniform key-row permutation sig; P goes to
// PV A-fragments via cvtpk + permlane32_swap (see round-5 notes).
// ---------------------------------------------------------------------------
__global__ __launch_bounds__(256, 2) void attn_kernel(
    const u16* __restrict__ qkv, const u16* __restrict__ vT,
    float* __restrict__ po, float* __restrict__ ps)
{
  __shared__ __align__(16) u16 Ks[2][4096];
  __shared__ __align__(16) u16 Vs[2][4096];
  int tid = threadIdx.x;
  int lane = tid & 63, wid = tid >> 6;
  int l15 = lane & 15, quad = lane >> 4;
  int bz = blockIdx.z;
  int b = bz >> 1, half = bz & 1;
  int h = blockIdx.y;
  int q0 = blockIdx.x * 128 + wid * 32;
  int k0 = half * 1024;  // key offset of this half

  const u16* qbA = qkv + (size_t)(b * 2048 + q0 + l15) * 3072 + h * 64 + (quad << 3);
  short8 qA0 = *(const short8*)qbA;
  short8 qA1 = *(const short8*)(qbA + 32);
  const u16* qbB = qbA + (size_t)16 * 3072;
  short8 qB0 = *(const short8*)qbB;
  short8 qB1 = *(const short8*)(qbB + 32);

  // staging (K and V): 16B/lane, XOR-swizzled source columns
  int srow = tid >> 3;
  int gc8 = ((tid & 7) ^ (srow & 7)) << 3;
  const u16* kg = qkv + (size_t)(b * 2048 + k0 + srow) * 3072 + 1024 + h * 64 + gc8;
  const u16* vg = vT + (size_t)(h * 64 + srow) * 4096 + b * 2048 + k0 + gc8;
  u16* lk = &Ks[0][wid * 512];
  u16* lv = &Vs[0][wid * 512];

  // uniform K A-operand row permutation sig (same for all subs)
  int lq = l15 >> 2;
  int rs = ((((lq & 1) << 1) | (lq >> 1)) << 2) | (l15 & 3);
  int sk = rs & 7;

  fx4 oaccA[4], oaccB[4];
  float sumA = 0.0f, sumB = 0.0f;
#pragma unroll
  for (int i = 0; i < 4; ++i) {
    oaccA[i] = fx4{0.f, 0.f, 0.f, 0.f};
    oaccB[i] = fx4{0.f, 0.f, 0.f, 0.f};
  }

  load16(kg,             lk);
  load16(kg + 32 * 3072, lk + 2048);
  load16(vg,             lv);
  load16(vg + 32 * 4096, lv + 2048);

  int swz = l15 & 7;
  const float SC = 0.18033688011112042f;  // (1/8) * log2(e)
  for (int kt = 0; kt < 16; ++kt) {
    __syncthreads();
    if (kt + 1 < 16) {
      int buf = (kt + 1) & 1;
      const u16* kgn = kg + (size_t)(kt + 1) * 64 * 3072;
      const u16* vgn = vg + (kt + 1) * 64;
      load16(kgn,             lk + buf * 4096);
      load16(kgn + 32 * 3072, lk + buf * 4096 + 2048);
      load16(vgn,             lv + buf * 4096);
      load16(vgn + 32 * 4096, lv + buf * 4096 + 2048);
    }
    const u16* Kb = Ks[kt & 1];
    const u16* Vb = Vs[kt & 1];

    // QK^T swapped, K fragment shared by both q-groups
    fx4 scA[4], scB[4];
    __builtin_amdgcn_s_setprio(1);
#pragma unroll
    for (int sub = 0; sub < 4; ++sub) {
      const u16* rp = &Kb[(sub * 16 + rs) * 64];
      short8 kf0 = *(const short8*)&rp[((quad ^ sk) & 7) << 3];
      short8 kf1 = *(const short8*)&rp[(((4 | quad) ^ sk) & 7) << 3];
      scA[sub] = fx4{0.f, 0.f, 0.f, 0.f};
      scA[sub] = __builtin_amdgcn_mfma_f32_16x16x32_bf16(kf0, qA0, scA[sub], 0, 0, 0);
      scA[sub] = __builtin_amdgcn_mfma_f32_16x16x32_bf16(kf1, qA1, scA[sub], 0, 0, 0);
      scB[sub] = fx4{0.f, 0.f, 0.f, 0.f};
      scB[sub] = __builtin_amdgcn_mfma_f32_16x16x32_bf16(kf0, qB0, scB[sub], 0, 0, 0);
      scB[sub] = __builtin_amdgcn_mfma_f32_16x16x32_bf16(kf1, qB1, scB[sub], 0, 0, 0);
    }
    __builtin_amdgcn_s_setprio(0);

    // softmax numerators in-register (exp2 with folded scale)
    u32 WA[4][2], WB[4][2];
    float psA = 0.0f, psB = 0.0f;
#pragma unroll
    for (int sub = 0; sub < 4; ++sub) {
      float a0 = __builtin_amdgcn_exp2f(scA[sub][0] * SC);
      float a1 = __builtin_amdgcn_exp2f(scA[sub][1] * SC);
      float a2 = __builtin_amdgcn_exp2f(scA[sub][2] * SC);
      float a3 = __builtin_amdgcn_exp2f(scA[sub][3] * SC);
      psA += (a0 + a1) + (a2 + a3);
      WA[sub][0] = cvtpk(a0, a1);
      WA[sub][1] = cvtpk(a2, a3);
      float b0 = __builtin_amdgcn_exp2f(scB[sub][0] * SC);
      float b1 = __builtin_amdgcn_exp2f(scB[sub][1] * SC);
      float b2 = __builtin_amdgcn_exp2f(scB[sub][2] * SC);
      float b3 = __builtin_amdgcn_exp2f(scB[sub][3] * SC);
      psB += (b0 + b1) + (b2 + b3);
      WB[sub][0] = cvtpk(b0, b1);
      WB[sub][1] = cvtpk(b2, b3);
    }
    sumA += psA;
    sumB += psB;

    // exchange with quad q^2 partner (lanes l <-> l^32); uniform slot map
    ux2 eA00 = __builtin_amdgcn_permlane32_swap(WA[0][0], WA[1][0], false, false);
    ux2 eA01 = __builtin_amdgcn_permlane32_swap(WA[0][1], WA[1][1], false, false);
    ux2 eA10 = __builtin_amdgcn_permlane32_swap(WA[2][0], WA[3][0], false, false);
    ux2 eA11 = __builtin_amdgcn_permlane32_swap(WA[2][1], WA[3][1], false, false);
    short8 pa1A = __builtin_bit_cast(short8, ux4{eA00[0], eA01[0], eA00[1], eA01[1]});
    short8 pa2A = __builtin_bit_cast(short8, ux4{eA10[0], eA11[0], eA10[1], eA11[1]});
    ux2 eB00 = __builtin_amdgcn_permlane32_swap(WB[0][0], WB[1][0], false, false);
    ux2 eB01 = __builtin_amdgcn_permlane32_swap(WB[0][1], WB[1][1], false, false);
    ux2 eB10 = __builtin_amdgcn_permlane32_swap(WB[2][0], WB[3][0], false, false);
    ux2 eB11 = __builtin_amdgcn_permlane32_swap(WB[2][1], WB[3][1], false, false);
    short8 pa1B = __builtin_bit_cast(short8, ux4{eB00[0], eB01[0], eB00[1], eB01[1]});
    short8 pa2B = __builtin_bit_cast(short8, ux4{eB10[0], eB11[0], eB10[1], eB11[1]});

    // PV: V fragment shared by both q-groups (plain b128, conflict-free)
    __builtin_amdgcn_s_setprio(1);
#pragma unroll
    for (int dt = 0; dt < 4; ++dt) {
      const u16* rp = &Vb[(dt * 16 + l15) * 64];
      short8 vf0 = *(const short8*)&rp[((quad ^ swz) & 7) << 3];
      short8 vf1 = *(const short8*)&rp[(((4 | quad) ^ swz) & 7) << 3];
      oaccA[dt] = __builtin_amdgcn_mfma_f32_16x16x32_bf16(pa1A, vf0, oaccA[dt], 0, 0, 0);
      oaccA[dt] = __builtin_amdgcn_mfma_f32_16x16x32_bf16(pa2A, vf1, oaccA[dt], 0, 0, 0);
      oaccB[dt] = __builtin_amdgcn_mfma_f32_16x16x32_bf16(pa1B, vf0, oaccB[dt], 0, 0, 0);
      oaccB[dt] = __builtin_amdgcn_mfma_f32_16x16x32_bf16(pa2B, vf1, oaccB[dt], 0, 0, 0);
    }
    __builtin_amdgcn_s_setprio(0);
  }
  // partial denominators: reduce the 4 quads sharing each l15
  sumA += __shfl_xor(sumA, 16, 64);
  sumA += __shfl_xor(sumA, 32, 64);
  sumB += __shfl_xor(sumB, 16, 64);
  sumB += __shfl_xor(sumB, 32, 64);
  if (lane < 16) {
    size_t rowA = (size_t)(b * 2048 + q0 + lane);
    ps[(rowA * 16 + h) * 2 + half] = sumA;
    ps[((rowA + 16) * 16 + h) * 2 + half] = sumB;
  }
  // unnormalized partial O (f32)
  float* pob = po + (size_t)half * 4194304;
#pragma unroll
  for (int dt = 0; dt < 4; ++dt) {
    int col = h * 64 + dt * 16 + l15;
#pragma unroll
    for (int r = 0; r < 4; ++r) {
      size_t rowA = (size_t)(b * 2048 + q0 + (quad << 2) + r);
      pob[rowA * 1024 + col] = oaccA[dt][r];
      pob[(rowA + 16) * 1024 + col] = oaccB[dt][r];
    }
  }
}

// ---------------------------------------------------------------------------
// Combine split-KV partials: o = bf16((po0 + po1) * 1/(ps0 + ps1)).
// grid 4096 (one row/block), block 256 (4 cols/thread).
// ---------------------------------------------------------------------------
__global__ __launch_bounds__(256) void attn_combine_kernel(
    const float* __restrict__ po, const float* __restrict__ ps,
    u16* __restrict__ o)
{
  int row = blockIdx.x, tid = threadIdx.x;
  size_t base = (size_t)row * 1024 + tid * 4;
  fx4 a = *(const fx4*)(po + base);
  fx4 c = *(const fx4*)(po + 4194304 + base);
  int h = (tid * 4) >> 6;
  const float* pr = ps + ((size_t)row * 16 + h) * 2;
  float inv = 1.0f / (pr[0] + pr[1]);
  u16 o4[4];
#pragma unroll
  for (int i = 0; i < 4; ++i) o4[i] = f2b((a[i] + c[i]) * inv);
  *(uint2*)(o + base) = *(uint2*)o4;
}

// ---------------------------------------------------------------------------
// LN: LayerNorm(main0 + main1 + res + cbias[col]) * g + beta, row len 1024.
// main1 is the second split-K partial (always present); cbias nullable
// (folds the FFN2 column bias in, since the GEMM now emits raw partials).
// ---------------------------------------------------------------------------
__global__ __launch_bounds__(256) void ln_kernel(
    const float* __restrict__ main0, const float* __restrict__ main1,
    const float* __restrict__ res, const float* __restrict__ cbias,
    const float* __restrict__ g, const float* __restrict__ beta,
    u16* __restrict__ out_b, float* __restrict__ out_f)
{
  __shared__ float red[8];
  int row = blockIdx.x, tid = threadIdx.x;
  size_t base = (size_t)row * 1024 + tid * 4;
  fx4 v = *(const fx4*)(main0 + base);
  fx4 v1 = *(const fx4*)(main1 + base);
  fx4 rv = *(const fx4*)(res + base);
#pragma unroll
  for (int i = 0; i < 4; ++i) v[i] += v1[i] + rv[i];
  if (cbias) {
    fx4 cb = *(const fx4*)(cbias + tid * 4);
#pragma unroll
    for (int i = 0; i < 4; ++i) v[i] += cb[i];
  }
  float s = v[0] + v[1] + v[2] + v[3];
  float sq = v[0] * v[0] + v[1] * v[1] + v[2] * v[2] + v[3] * v[3];
#pragma unroll
  for (int off = 32; off >= 1; off >>= 1) {
    s += __shfl_xor(s, off, 64);
    sq += __shfl_xor(sq, off, 64);
  }
  int wid = tid >> 6, lane = tid & 63;
  if (lane == 0) { red[wid] = s; red[wid + 4] = sq; }
  __syncthreads();
  float S = red[0] + red[1] + red[2] + red[3];
  float SQ = red[4] + red[5] + red[6] + red[7];
  float mean = S * (1.0f / 1024.0f);
  float var = SQ * (1.0f / 1024.0f) - mean * mean;
  float rs = rsqrtf(var + 1e-5f);
  fx4 gv = *(const fx4*)(g + tid * 4);
  fx4 bv = *(const fx4*)(beta + tid * 4);
  float of[4];
#pragma unroll
  for (int i = 0; i < 4; ++i) of[i] = (v[i] - mean) * rs * gv[i] + bv[i];
  if (out_f) *(fx4*)(out_f + base) = *(const fx4*)of;
  if (out_b) {
    u16 o4[4];
#pragma unroll
    for (int i = 0; i < 4; ++i) o4[i] = f2b(of[i]);
    *(uint2*)(out_b + base) = *(uint2*)o4;
  }
}

// ---------------------------------------------------------------------------
// Workspace (peak 88 MiB, liveness-checked):
//   xb    bf16 [ 0, 8)M   (dead after QKV gemm)
//   wqkvT bf16 [ 8,14)M   (dead after QKV gemm)
//   woT   bf16 [38,40)M   (dead after Wo-proj)
//   qkv   bf16 [40,64)M   (dead after attn)
//   vT    bf16 [64,72)M   (dead after attn)
//   po    f32  [ 0,32)M   attn split-KV partials (dead after combine)
//   ps    f32  [32,33)M   attn partial sums      (dead after combine)
//   ob    bf16 [72,80)M   (dead after Wo-proj)
//   aout  f32  [ 0,32)M   2 split-K partials (dead after LN1)
//   x1f   f32  [40,56)M   (live until LN2)
//   x1    bf16 [64,72)M   (dead after FFN1)
//   w1T   bf16 [56,64)M   (dead after FFN1)
//   w2T   bf16 [ 0, 8)M   (live until FFN2)
//   hbuf  bf16 [ 8,40)M   (live until FFN2)
//   ffn   f32  [56,88)M   2 split-K partials (live until LN2)
// ---------------------------------------------------------------------------
extern "C" void kernel_launch(void* const* d_in, const int* in_sizes, int n_in,
                              void* d_out, int out_size, void* d_ws, size_t ws_size,
                              hipStream_t stream) {
  (void)in_sizes; (void)n_in; (void)out_size; (void)ws_size;
  const float* x     = (const float*)d_in[0];
  const float* Wq    = (const float*)d_in[1];
  const float* Wk    = (const float*)d_in[2];
  const float* Wv    = (const float*)d_in[3];
  const float* Wo    = (const float*)d_in[4];
  const float* g1    = (const float*)d_in[5];
  const float* bb1   = (const float*)d_in[6];
  const float* W1    = (const float*)d_in[7];
  const float* bias1 = (const float*)d_in[8];
  const float* W2    = (const float*)d_in[9];
  const float* bias2 = (const float*)d_in[10];
  const float* g2    = (const float*)d_in[11];
  const float* bb2   = (const float*)d_in[12];

  char* ws = (char*)d_ws;
  const size_t MB = 1048576;
  u16* xb     = (u16*)(ws);
  u16* wqkvT  = (u16*)(ws + 8 * MB);
  u16* woT    = (u16*)(ws + 38 * MB);
  u16* qkv    = (u16*)(ws + 40 * MB);
  u16* vT     = (u16*)(ws + 64 * MB);
  u16* ob     = (u16*)(ws + 72 * MB);
  float* po   = (float*)(ws);            // 2 x 16MB attn partials
  float* ps   = (float*)(ws + 32 * MB);  // 512 KB partial sums
  float* aout = (float*)(ws);            // 2 partials, 16MB each
  u16* x1     = (u16*)(ws + 64 * MB);
  float* x1f  = (float*)(ws + 40 * MB);
  u16* w1T    = (u16*)(ws + 56 * MB);
  u16* w2T    = (u16*)(ws);
  u16* hbuf   = (u16*)(ws + 8 * MB);
  float* ffn  = (float*)(ws + 56 * MB);  // 2 partials, 16MB each

  dim3 tb(32, 8, 1);
  cvt_f2b_kernel<<<4096, 256, 0, stream>>>(x, xb);
  transpose_f2b_kernel<<<dim3(2, 32, 16), tb, 0, stream>>>(Wq, wqkvT,           1024, 64, 1024);
  transpose_f2b_kernel<<<dim3(2, 32, 16), tb, 0, stream>>>(Wk, wqkvT + 1048576, 1024, 64, 1024);
  transpose_f2b_kernel<<<dim3(2, 32, 16), tb, 0, stream>>>(Wv, wqkvT + 2097152, 1024, 64, 1024);
  transpose_f2b_kernel<<<dim3(32, 32, 1), tb, 0, stream>>>(Wo, woT, 1024, 1024, 1024);

  // qkv = x @ [Wq|Wk|Wv]  (bf16 out) — BK=32 (768-block grid, tail-friendly)
  gemm_bt<<<dim3(24, 32), 256, 0, stream>>>(xb, wqkvT, nullptr, qkv, 4096, 3072, 1024, 1);
  // vT = (V slice of qkv)^T
  transpose_b2b_kernel<<<dim3(32, 128), tb, 0, stream>>>(qkv + 2048, vT, 3072, 4096);
  // attention, split-KV: partials -> po/ps; combine -> ob (bf16)
  attn_kernel<<<dim3(16, 16, 4), 256, 0, stream>>>(qkv, vT, po, ps);
  attn_combine_kernel<<<4096, 256, 0, stream>>>(po, ps, ob);
  // aout partials = ob @ Wo  (f32, split-K=2, BK=64, XCD-swizzled)
  gemm_bt_k64<<<dim3(8, 32, 2), 256, 0, stream>>>(ob, woT, nullptr, aout, 4096, 1024, 1024, 0);
  // x1 = LN(aout0 + aout1 + x): bf16 (FFN1 operand) + f32 (LN2 residual)
  ln_kernel<<<4096, 256, 0, stream>>>(aout, aout + 4194304, x, nullptr, g1, bb1, x1, x1f);
  // lazy weight transposes into dead regions
  transpose_f2b_kernel<<<dim3(128, 32, 1), tb, 0, stream>>>(W1, w1T, 1024, 4096, 1024);
  transpose_f2b_kernel<<<dim3(32, 128, 1), tb, 0, stream>>>(W2, w2T, 4096, 1024, 4096);
  // hbuf = relu(x1 @ W1 + b1)  (bf16 out) — BK=64: 32 MFMA/barrier,
  // 1024 blocks = 2 clean rounds at 2 blocks/CU
  gemm_bt_k64<<<dim3(32, 32, 1), 256, 0, stream>>>(x1, w1T, bias1, hbuf, 4096, 4096, 1024, 1 | 2 | 4);
  // ffn partials = hbuf @ W2  (f32, split-K=2, BK=64, XCD-swizzled)
  gemm_bt_k64<<<dim3(8, 32, 2), 256, 0, stream>>>(hbuf, w2T, nullptr, ffn, 4096, 1024, 4096, 0);
  // out = LN(ffn0 + ffn1 + bias2 + x1f) -> f32 d_out
  ln_kernel<<<4096, 256, 0, stream>>>(ffn, ffn + 4194304, x1f, bias2, g2, bb2, nullptr, (float*)d_out);
}

// Round 11
// 347.771 us; speedup vs baseline: 1.0448x; 1.0285x over previous
//
#include <hip/hip_runtime.h>
#include <hip/hip_bf16.h>

typedef unsigned short u16;
typedef unsigned int u32;
typedef short short8 __attribute__((ext_vector_type(8)));
typedef float fx4 __attribute__((ext_vector_type(4)));
typedef u32 ux4 __attribute__((ext_vector_type(4)));
typedef u32 ux2 __attribute__((ext_vector_type(2)));

__device__ __forceinline__ float b2f(u16 x) {
  return __uint_as_float(((u32)x) << 16);
}
__device__ __forceinline__ u16 f2b(float f) {
  u32 u = __float_as_uint(f);
  u += 0x7fffu + ((u >> 16) & 1u);  // RNE
  return (u16)(u >> 16);
}
// HW packed f32x2 -> bf16x2 (RNE). No builtin on gfx950; inline asm per T12.
__device__ __forceinline__ u32 cvtpk(float a, float b) {
  u32 r;
  asm("v_cvt_pk_bf16_f32 %0, %1, %2" : "=v"(r) : "v"(a), "v"(b));
  return r;
}
// scale all 8 bf16 lanes of a fragment by s (one-time cost; MFMA linearity
// lets us fold the softmax scale into Q instead of 32 muls per tile)
__device__ __forceinline__ short8 scale8(short8 v, float s) {
  u32 r0 = cvtpk(b2f((u16)v[0]) * s, b2f((u16)v[1]) * s);
  u32 r1 = cvtpk(b2f((u16)v[2]) * s, b2f((u16)v[3]) * s);
  u32 r2 = cvtpk(b2f((u16)v[4]) * s, b2f((u16)v[5]) * s);
  u32 r3 = cvtpk(b2f((u16)v[6]) * s, b2f((u16)v[7]) * s);
  return __builtin_bit_cast(short8, ux4{r0, r1, r2, r3});
}

// Async global->LDS DMA, 16B per lane. LDS dest = wave-uniform base + lane*16.
__device__ __forceinline__ void load16(const u16* g, u16* l) {
  __builtin_amdgcn_global_load_lds(
      (__attribute__((address_space(1))) void*)(u16*)g,
      (__attribute__((address_space(3))) void*)l, 16, 0, 0);
}

// ---------------------------------------------------------------------------
// f32 -> bf16 elementwise. grid = n/1024, block 256 (4 elems/thread).
// ---------------------------------------------------------------------------
__global__ __launch_bounds__(256) void cvt_f2b_kernel(
    const float* __restrict__ in, u16* __restrict__ out)
{
  int i = (blockIdx.x * 256 + threadIdx.x) * 4;
  fx4 v = *(const fx4*)(in + i);
  u16 o4[4];
#pragma unroll
  for (int j = 0; j < 4; ++j) o4[j] = f2b(v[j]);
  *(uint2*)(out + i) = *(uint2*)o4;
}

// ---------------------------------------------------------------------------
// Fused transpose + f32->bf16: out[batch][c][r] = bf16(in[batch][r][c]).
// grid: (C/32, R/32, nbatch), block: (32,8). out batch stride = C * out_ld.
// ---------------------------------------------------------------------------
__global__ __launch_bounds__(256) void transpose_f2b_kernel(
    const float* __restrict__ in, u16* __restrict__ out,
    int R, int C, int out_ld)
{
  __shared__ __align__(16) u16 tile[32][33];
  int tx = threadIdx.x, ty = threadIdx.y;
  int c0 = blockIdx.x * 32, r0 = blockIdx.y * 32;
  const float* inb = in + (size_t)blockIdx.z * R * C;
  u16* outb = out + (size_t)blockIdx.z * C * out_ld;
#pragma unroll
  for (int i = 0; i < 4; ++i)
    tile[ty + i * 8][tx] = f2b(inb[(size_t)(r0 + ty + i * 8) * C + c0 + tx]);
  __syncthreads();
#pragma unroll
  for (int i = 0; i < 4; ++i)
    outb[(size_t)(c0 + ty + i * 8) * out_ld + r0 + tx] = tile[tx][ty + i * 8];
}

// ---------------------------------------------------------------------------
// bf16 strided transpose: out[c][r] = in[r*in_ld + c]. grid (C/32, R/32).
// ---------------------------------------------------------------------------
__global__ __launch_bounds__(256) void transpose_b2b_kernel(
    const u16* __restrict__ in, u16* __restrict__ out, int in_ld, int out_ld)
{
  __shared__ __align__(16) u16 tile[32][33];
  int tx = threadIdx.x, ty = threadIdx.y;
  int c0 = blockIdx.x * 32, r0 = blockIdx.y * 32;
#pragma unroll
  for (int i = 0; i < 4; ++i)
    tile[ty + i * 8][tx] = in[(size_t)(r0 + ty + i * 8) * in_ld + c0 + tx];
  __syncthreads();
#pragma unroll
  for (int i = 0; i < 4; ++i)
    out[(size_t)(c0 + ty + i * 8) * out_ld + r0 + tx] = tile[tx][ty + i * 8];
}

// ---------------------------------------------------------------------------
// C[M,N] = A[M,K] * BT[N,K]^T; bf16 in, fp32 acc. 128x128 tile, BK=32,
// 4 waves x 64x64. global_load_lds dbuf staging, 1 barrier/K-tile, XOR swizzle.
// flags: 1 = store bf16 (else fp32), 2 = add f32 bias[col], 4 = relu.
// Used for QKV (768-block grid where BK=64's 2-blocks/CU would leave a
// half-idle tail round).
// ---------------------------------------------------------------------------
__global__ __launch_bounds__(256, 2) void gemm_bt(
    const u16* __restrict__ A, const u16* __restrict__ BT,
    const float* __restrict__ bias, void* __restrict__ Cp,
    int M, int N, int K, int flags)
{
  __shared__ __align__(16) u16 As[2][4096];
  __shared__ __align__(16) u16 Bs[2][4096];
  int tid = threadIdx.x;
  int lane = tid & 63, wid = tid >> 6;
  int l15 = lane & 15, quad = lane >> 4;
  int wm = wid >> 1, wn = wid & 1;
  int m0 = blockIdx.y * 128, n0 = blockIdx.x * 128;

  int srow = wid * 16 + (lane >> 2);
  int sswz = (((lane >> 2) & 3) + ((lane >> 4) & 3)) & 3;
  int gch = (lane & 3) ^ sswz;
  const u16* gA = A + (size_t)(m0 + srow) * K + gch * 8;
  const u16* gB = BT + (size_t)(n0 + srow) * K + gch * 8;
  size_t gstep = (size_t)64 * K;
  u16* lA = &As[0][wid * 512];
  u16* lB = &Bs[0][wid * 512];

  int rswz = ((l15 & 3) + (l15 >> 2)) & 3;
  int rphys = ((quad ^ rswz) & 3) << 3;

  fx4 acc[4][4];
#pragma unroll
  for (int i = 0; i < 4; ++i)
#pragma unroll
    for (int j = 0; j < 4; ++j) acc[i][j] = fx4{0.f, 0.f, 0.f, 0.f};

  int nt = K >> 5;
  load16(gA,         lA);
  load16(gA + gstep, lA + 2048);
  load16(gB,         lB);
  load16(gB + gstep, lB + 2048);

  for (int kt = 0; kt < nt; ++kt) {
    __syncthreads();
    if (kt + 1 < nt) {
      int buf = (kt + 1) & 1;
      const u16* ga = gA + (kt + 1) * 32;
      const u16* gb = gB + (kt + 1) * 32;
      load16(ga,         lA + buf * 4096);
      load16(ga + gstep, lA + buf * 4096 + 2048);
      load16(gb,         lB + buf * 4096);
      load16(gb + gstep, lB + buf * 4096 + 2048);
    }
    const u16* Ab = As[kt & 1];
    const u16* Bb = Bs[kt & 1];
    short8 af[4], bf[4];
#pragma unroll
    for (int t = 0; t < 4; ++t)
      af[t] = *(const short8*)&Ab[(wm * 64 + t * 16 + l15) * 32 + rphys];
#pragma unroll
    for (int t = 0; t < 4; ++t)
      bf[t] = *(const short8*)&Bb[(wn * 64 + t * 16 + l15) * 32 + rphys];
#pragma unroll
    for (int tm = 0; tm < 4; ++tm)
#pragma unroll
      for (int tn = 0; tn < 4; ++tn)
        acc[tm][tn] = __builtin_amdgcn_mfma_f32_16x16x32_bf16(
            af[tm], bf[tn], acc[tm][tn], 0, 0, 0);
  }

  bool obf = flags & 1, hb = flags & 2, rl = flags & 4;
#pragma unroll
  for (int tn = 0; tn < 4; ++tn) {
    int col = n0 + wn * 64 + tn * 16 + l15;
    float bv = hb ? bias[col] : 0.0f;
#pragma unroll
    for (int tm = 0; tm < 4; ++tm) {
      int row = m0 + wm * 64 + tm * 16 + (quad << 2);
#pragma unroll
      for (int r = 0; r < 4; ++r) {
        float v = acc[tm][tn][r] + bv;
        if (rl) v = fmaxf(v, 0.0f);
        size_t idx = (size_t)(row + r) * N + col;
        if (obf) ((u16*)Cp)[idx] = f2b(v);
        else ((float*)Cp)[idx] = v;
      }
    }
  }
}

// ---------------------------------------------------------------------------
// BK=64 variant for the latency-limited GEMMs (Wo-proj, FFN1, FFN2).
// 128x128 tile, 64 KB LDS (2 blocks/CU), 32 MFMA per barrier (2x gemm_bt) so
// the staged-load latency is covered and the barrier/vmcnt drain count halves
// (measured: FFN2 round 8, FFN1 63->49 us round 10). 8-chunk XOR:
//   staging: LDS[row][c] = src[(c ^ (row&7))*8 ..], per-thread constant
//   read:    chunk = ((s<<2)|quad) ^ (l15&7)  (s = k-substep 0/1)
// Optional split-K over blockIdx.z into partial f32 buffers at Cp + z*M*N,
// with the bijective XCD-chunked swizzle when gridDim.z > 1.
// flags as gemm_bt.
// ---------------------------------------------------------------------------
__global__ __launch_bounds__(256, 2) void gemm_bt_k64(
    const u16* __restrict__ A, const u16* __restrict__ BT,
    const float* __restrict__ bias, void* __restrict__ Cp,
    int M, int N, int K, int flags)
{
  __shared__ __align__(16) u16 As[2][8192];
  __shared__ __align__(16) u16 Bs[2][8192];
  int tid = threadIdx.x;
  int lane = tid & 63, wid = tid >> 6;
  int l15 = lane & 15, quad = lane >> 4;
  int wm = wid >> 1, wn = wid & 1;

  int bx = blockIdx.x, by = blockIdx.y, bz = blockIdx.z;
  if (gridDim.z > 1) {
    int nx = gridDim.x, ny = gridDim.y;
    int total = nx * ny * (int)gridDim.z;
    int cpx = total >> 3;
    int lin = bx + nx * (by + ny * bz);
    int swb = (lin & 7) * cpx + (lin >> 3);
    bx = swb % nx;
    int t2 = swb / nx;
    by = t2 % ny;
    bz = t2 / ny;
  }
  int m0 = by * 128, n0 = bx * 128;
  int kc = K / (int)gridDim.z;  // multiple of 64

  // staging: wave covers 8 rows/load16; 4 sub-loads span 128 rows (+32 each)
  int r8 = lane >> 3;           // row & 7
  int clog = (lane & 7) ^ r8;   // source chunk for phys chunk lane&7
  const u16* gA = A + (size_t)(m0 + wid * 8 + r8) * K + bz * kc + clog * 8;
  const u16* gB = BT + (size_t)(n0 + wid * 8 + r8) * K + bz * kc + clog * 8;
  size_t gstep = (size_t)32 * K;
  u16* lA = &As[0][wid * 512];
  u16* lB = &Bs[0][wid * 512];

  fx4 acc[4][4];
#pragma unroll
  for (int i = 0; i < 4; ++i)
#pragma unroll
    for (int j = 0; j < 4; ++j) acc[i][j] = fx4{0.f, 0.f, 0.f, 0.f};

  int nt = kc >> 6;
#pragma unroll
  for (int i = 0; i < 4; ++i) {
    load16(gA + i * gstep, lA + i * 2048);
    load16(gB + i * gstep, lB + i * 2048);
  }

  for (int kt = 0; kt < nt; ++kt) {
    __syncthreads();
    if (kt + 1 < nt) {
      int buf = (kt + 1) & 1;
      const u16* ga = gA + (kt + 1) * 64;
      const u16* gb = gB + (kt + 1) * 64;
#pragma unroll
      for (int i = 0; i < 4; ++i) {
        load16(ga + i * gstep, lA + buf * 8192 + i * 2048);
        load16(gb + i * gstep, lB + buf * 8192 + i * 2048);
      }
    }
    const u16* Ab = As[kt & 1];
    const u16* Bb = Bs[kt & 1];
#pragma unroll
    for (int s = 0; s < 2; ++s) {
      int ch = (((s << 2) | quad) ^ (l15 & 7)) << 3;
      short8 af[4], bf[4];
#pragma unroll
      for (int t = 0; t < 4; ++t)
        af[t] = *(const short8*)&Ab[(wm * 64 + t * 16 + l15) * 64 + ch];
#pragma unroll
      for (int t = 0; t < 4; ++t)
        bf[t] = *(const short8*)&Bb[(wn * 64 + t * 16 + l15) * 64 + ch];
#pragma unroll
      for (int tm = 0; tm < 4; ++tm)
#pragma unroll
        for (int tn = 0; tn < 4; ++tn)
          acc[tm][tn] = __builtin_amdgcn_mfma_f32_16x16x32_bf16(
              af[tm], bf[tn], acc[tm][tn], 0, 0, 0);
    }
  }

  bool obf = flags & 1, hb = flags & 2, rl = flags & 4;
  u16* cb16 = (u16*)Cp + (size_t)bz * M * N;
  float* cf32 = (float*)Cp + (size_t)bz * M * N;
#pragma unroll
  for (int tn = 0; tn < 4; ++tn) {
    int col = n0 + wn * 64 + tn * 16 + l15;
    float bv = hb ? bias[col] : 0.0f;
#pragma unroll
    for (int tm = 0; tm < 4; ++tm) {
      int row = m0 + wm * 64 + tm * 16 + (quad << 2);
#pragma unroll
      for (int r = 0; r < 4; ++r) {
        float v = acc[tm][tn][r] + bv;
        if (rl) v = fmaxf(v, 0.0f);
        size_t idx = (size_t)(row + r) * N + col;
        if (obf) cb16[idx] = f2b(v);
        else cf32[idx] = v;
      }
    }
  }
}

// ---------------------------------------------------------------------------
// Flash attention v2, in-register P, 32 queries per wave (2 x 16-q groups).
// Single-kernel (split-KV reverted: the f32-partial write + combine pass cost
// ~10us > the 4.5us occupancy gain; attn is VALU-bound, not latency-bound).
// qkv[4096][3072] bf16 (q|k|v); vT[1024][4096] bf16; o[4096][1024] bf16.
// grid: (S/128, H, B); block 256 (4 waves x 32q = 128 q/block).
// Q is PRE-SCALED by (1/8)*log2e at load (MFMA linearity) so the per-tile
// exp2 inputs need no multiply — kills 32 v_mul per tile (VALU is the
// binding pipe: 43% busy vs 27% MfmaUtil, round 10).
// QK^T swapped (mfma(K,Q)) with UNIFORM key-row permutation for all subs:
//   row = sub*16 + sig(l15), sig(l15) = g(l15>>2)*4 + (l15&3), g={0,2,1,3}.
// After permlane32_swap the words map to PV A-fragment slots uniformly:
// pa = {e0[0],e1[0],e0[1],e1[1]}. V keeps its natural layout (b128 reads).
// Row sums: per-lane f32 accumulate + shfl reduce at the end.
// ---------------------------------------------------------------------------
__global__ __launch_bounds__(256, 2) void attn_kernel(
    const u16* __restrict__ qkv, const u16* __restrict__ vT,
    u16* __restrict__ o)
{
  __shared__ __align__(16) u16 Ks[2][4096];
  __shared__ __align__(16) u16 Vs[2][4096];
  int tid = threadIdx.x;
  int lane = tid & 63, wid = tid >> 6;
  int l15 = lane & 15, quad = lane >> 4;
  int b = blockIdx.z, h = blockIdx.y;
  int q0 = blockIdx.x * 128 + wid * 32;

  const float SC = 0.18033688011112042f;  // (1/8) * log2(e)
  const u16* qbA = qkv + (size_t)(b * 2048 + q0 + l15) * 3072 + h * 64 + (quad << 3);
  short8 qA0 = scale8(*(const short8*)qbA, SC);
  short8 qA1 = scale8(*(const short8*)(qbA + 32), SC);
  const u16* qbB = qbA + (size_t)16 * 3072;
  short8 qB0 = scale8(*(const short8*)qbB, SC);
  short8 qB1 = scale8(*(const short8*)(qbB + 32), SC);

  // staging (K and V): 16B/lane, XOR-swizzled source columns
  int srow = tid >> 3;
  int gc8 = ((tid & 7) ^ (srow & 7)) << 3;
  const u16* kg = qkv + (size_t)(b * 2048 + srow) * 3072 + 1024 + h * 64 + gc8;
  const u16* vg = vT + (size_t)(h * 64 + srow) * 4096 + b * 2048 + gc8;
  u16* lk = &Ks[0][wid * 512];
  u16* lv = &Vs[0][wid * 512];

  // uniform K A-operand row permutation sig (same for all subs)
  int lq = l15 >> 2;
  int rs = ((((lq & 1) << 1) | (lq >> 1)) << 2) | (l15 & 3);
  int sk = rs & 7;

  fx4 oaccA[4], oaccB[4];
  float sumA = 0.0f, sumB = 0.0f;
#pragma unroll
  for (int i = 0; i < 4; ++i) {
    oaccA[i] = fx4{0.f, 0.f, 0.f, 0.f};
    oaccB[i] = fx4{0.f, 0.f, 0.f, 0.f};
  }

  load16(kg,             lk);
  load16(kg + 32 * 3072, lk + 2048);
  load16(vg,             lv);
  load16(vg + 32 * 4096, lv + 2048);

  int swz = l15 & 7;
  for (int kt = 0; kt < 32; ++kt) {
    __syncthreads();
    if (kt + 1 < 32) {
      int buf = (kt + 1) & 1;
      const u16* kgn = kg + (size_t)(kt + 1) * 64 * 3072;
      const u16* vgn = vg + (kt + 1) * 64;
      load16(kgn,             lk + buf * 4096);
      load16(kgn + 32 * 3072, lk + buf * 4096 + 2048);
      load16(vgn,             lv + buf * 4096);
      load16(vgn + 32 * 4096, lv + buf * 4096 + 2048);
    }
    const u16* Kb = Ks[kt & 1];
    const u16* Vb = Vs[kt & 1];

    // QK^T swapped, K fragment shared by both q-groups
    fx4 scA[4], scB[4];
    __builtin_amdgcn_s_setprio(1);
#pragma unroll
    for (int sub = 0; sub < 4; ++sub) {
      const u16* rp = &Kb[(sub * 16 + rs) * 64];
      short8 kf0 = *(const short8*)&rp[((quad ^ sk) & 7) << 3];
      short8 kf1 = *(const short8*)&rp[(((4 | quad) ^ sk) & 7) << 3];
      scA[sub] = fx4{0.f, 0.f, 0.f, 0.f};
      scA[sub] = __builtin_amdgcn_mfma_f32_16x16x32_bf16(kf0, qA0, scA[sub], 0, 0, 0);
      scA[sub] = __builtin_amdgcn_mfma_f32_16x16x32_bf16(kf1, qA1, scA[sub], 0, 0, 0);
      scB[sub] = fx4{0.f, 0.f, 0.f, 0.f};
      scB[sub] = __builtin_amdgcn_mfma_f32_16x16x32_bf16(kf0, qB0, scB[sub], 0, 0, 0);
      scB[sub] = __builtin_amdgcn_mfma_f32_16x16x32_bf16(kf1, qB1, scB[sub], 0, 0, 0);
    }
    __builtin_amdgcn_s_setprio(0);

    // softmax numerators in-register (exp2 directly; scale folded into Q)
    u32 WA[4][2], WB[4][2];
    float psA = 0.0f, psB = 0.0f;
#pragma unroll
    for (int sub = 0; sub < 4; ++sub) {
      float a0 = __builtin_amdgcn_exp2f(scA[sub][0]);
      float a1 = __builtin_amdgcn_exp2f(scA[sub][1]);
      float a2 = __builtin_amdgcn_exp2f(scA[sub][2]);
      float a3 = __builtin_amdgcn_exp2f(scA[sub][3]);
      psA += (a0 + a1) + (a2 + a3);
      WA[sub][0] = cvtpk(a0, a1);
      WA[sub][1] = cvtpk(a2, a3);
      float b0 = __builtin_amdgcn_exp2f(scB[sub][0]);
      float b1 = __builtin_amdgcn_exp2f(scB[sub][1]);
      float b2 = __builtin_amdgcn_exp2f(scB[sub][2]);
      float b3 = __builtin_amdgcn_exp2f(scB[sub][3]);
      psB += (b0 + b1) + (b2 + b3);
      WB[sub][0] = cvtpk(b0, b1);
      WB[sub][1] = cvtpk(b2, b3);
    }
    sumA += psA;
    sumB += psB;

    // exchange with quad q^2 partner (lanes l <-> l^32); uniform slot map
    ux2 eA00 = __builtin_amdgcn_permlane32_swap(WA[0][0], WA[1][0], false, false);
    ux2 eA01 = __builtin_amdgcn_permlane32_swap(WA[0][1], WA[1][1], false, false);
    ux2 eA10 = __builtin_amdgcn_permlane32_swap(WA[2][0], WA[3][0], false, false);
    ux2 eA11 = __builtin_amdgcn_permlane32_swap(WA[2][1], WA[3][1], false, false);
    short8 pa1A = __builtin_bit_cast(short8, ux4{eA00[0], eA01[0], eA00[1], eA01[1]});
    short8 pa2A = __builtin_bit_cast(short8, ux4{eA10[0], eA11[0], eA10[1], eA11[1]});
    ux2 eB00 = __builtin_amdgcn_permlane32_swap(WB[0][0], WB[1][0], false, false);
    ux2 eB01 = __builtin_amdgcn_permlane32_swap(WB[0][1], WB[1][1], false, false);
    ux2 eB10 = __builtin_amdgcn_permlane32_swap(WB[2][0], WB[3][0], false, false);
    ux2 eB11 = __builtin_amdgcn_permlane32_swap(WB[2][1], WB[3][1], false, false);
    short8 pa1B = __builtin_bit_cast(short8, ux4{eB00[0], eB01[0], eB00[1], eB01[1]});
    short8 pa2B = __builtin_bit_cast(short8, ux4{eB10[0], eB11[0], eB10[1], eB11[1]});

    // PV: V fragment shared by both q-groups (plain b128, conflict-free)
    __builtin_amdgcn_s_setprio(1);
#pragma unroll
    for (int dt = 0; dt < 4; ++dt) {
      const u16* rp = &Vb[(dt * 16 + l15) * 64];
      short8 vf0 = *(const short8*)&rp[((quad ^ swz) & 7) << 3];
      short8 vf1 = *(const short8*)&rp[(((4 | quad) ^ swz) & 7) << 3];
      oaccA[dt] = __builtin_amdgcn_mfma_f32_16x16x32_bf16(pa1A, vf0, oaccA[dt], 0, 0, 0);
      oaccA[dt] = __builtin_amdgcn_mfma_f32_16x16x32_bf16(pa2A, vf1, oaccA[dt], 0, 0, 0);
      oaccB[dt] = __builtin_amdgcn_mfma_f32_16x16x32_bf16(pa1B, vf0, oaccB[dt], 0, 0, 0);
      oaccB[dt] = __builtin_amdgcn_mfma_f32_16x16x32_bf16(pa2B, vf1, oaccB[dt], 0, 0, 0);
    }
    __builtin_amdgcn_s_setprio(0);
  }
  // denominators: reduce the 4 quads sharing each l15, then fetch per-row
  sumA += __shfl_xor(sumA, 16, 64);
  sumA += __shfl_xor(sumA, 32, 64);
  sumB += __shfl_xor(sumB, 16, 64);
  sumB += __shfl_xor(sumB, 32, 64);
  fx4 invA, invB;
#pragma unroll
  for (int r = 0; r < 4; ++r) {
    invA[r] = 1.0f / __shfl(sumA, (quad << 2) + r, 64);
    invB[r] = 1.0f / __shfl(sumB, (quad << 2) + r, 64);
  }
#pragma unroll
  for (int dt = 0; dt < 4; ++dt) {
    int col = h * 64 + dt * 16 + l15;
#pragma unroll
    for (int r = 0; r < 4; ++r) {
      size_t rowA = (size_t)(b * 2048 + q0 + (quad << 2) + r);
      o[rowA * 1024 + col] = f2b(oaccA[dt][r] * invA[r]);
      o[(rowA + 16) * 1024 + col] = f2b(oaccB[dt][r] * invB[r]);
    }
  }
}

// ---------------------------------------------------------------------------
// LN: LayerNorm(main0 + main1 + res + cbias[col]) * g + beta, row len 1024.
// main1 is the second split-K partial (always present); cbias nullable
// (folds the FFN2 column bias in, since the GEMM now emits raw partials).
// ---------------------------------------------------------------------------
__global__ __launch_bounds__(256) void ln_kernel(
    const float* __restrict__ main0, const float* __restrict__ main1,
    const float* __restrict__ res, const float* __restrict__ cbias,
    const float* __restrict__ g, const float* __restrict__ beta,
    u16* __restrict__ out_b, float* __restrict__ out_f)
{
  __shared__ float red[8];
  int row = blockIdx.x, tid = threadIdx.x;
  size_t base = (size_t)row * 1024 + tid * 4;
  fx4 v = *(const fx4*)(main0 + base);
  fx4 v1 = *(const fx4*)(main1 + base);
  fx4 rv = *(const fx4*)(res + base);
#pragma unroll
  for (int i = 0; i < 4; ++i) v[i] += v1[i] + rv[i];
  if (cbias) {
    fx4 cb = *(const fx4*)(cbias + tid * 4);
#pragma unroll
    for (int i = 0; i < 4; ++i) v[i] += cb[i];
  }
  float s = v[0] + v[1] + v[2] + v[3];
  float sq = v[0] * v[0] + v[1] * v[1] + v[2] * v[2] + v[3] * v[3];
#pragma unroll
  for (int off = 32; off >= 1; off >>= 1) {
    s += __shfl_xor(s, off, 64);
    sq += __shfl_xor(sq, off, 64);
  }
  int wid = tid >> 6, lane = tid & 63;
  if (lane == 0) { red[wid] = s; red[wid + 4] = sq; }
  __syncthreads();
  float S = red[0] + red[1] + red[2] + red[3];
  float SQ = red[4] + red[5] + red[6] + red[7];
  float mean = S * (1.0f / 1024.0f);
  float var = SQ * (1.0f / 1024.0f) - mean * mean;
  float rs = rsqrtf(var + 1e-5f);
  fx4 gv = *(const fx4*)(g + tid * 4);
  fx4 bv = *(const fx4*)(beta + tid * 4);
  float of[4];
#pragma unroll
  for (int i = 0; i < 4; ++i) of[i] = (v[i] - mean) * rs * gv[i] + bv[i];
  if (out_f) *(fx4*)(out_f + base) = *(const fx4*)of;
  if (out_b) {
    u16 o4[4];
#pragma unroll
    for (int i = 0; i < 4; ++i) o4[i] = f2b(of[i]);
    *(uint2*)(out_b + base) = *(uint2*)o4;
  }
}

// ---------------------------------------------------------------------------
// Workspace (peak 88 MiB, liveness-checked):
//   xb    bf16 [ 0, 8)M   (dead after QKV gemm)
//   wqkvT bf16 [ 8,14)M   (dead after QKV gemm)
//   woT   bf16 [38,40)M   (dead after Wo-proj)
//   qkv   bf16 [40,64)M   (dead after attn)
//   vT    bf16 [64,72)M   (dead after attn)
//   ob    bf16 [72,80)M   (dead after Wo-proj)
//   aout  f32  [ 0,32)M   2 split-K partials (dead after LN1)
//   x1f   f32  [40,56)M   (live until LN2)
//   x1    bf16 [64,72)M   (dead after FFN1)
//   w1T   bf16 [56,64)M   (dead after FFN1)
//   w2T   bf16 [ 0, 8)M   (live until FFN2)
//   hbuf  bf16 [ 8,40)M   (live until FFN2)
//   ffn   f32  [56,88)M   2 split-K partials (live until LN2)
// ---------------------------------------------------------------------------
extern "C" void kernel_launch(void* const* d_in, const int* in_sizes, int n_in,
                              void* d_out, int out_size, void* d_ws, size_t ws_size,
                              hipStream_t stream) {
  (void)in_sizes; (void)n_in; (void)out_size; (void)ws_size;
  const float* x     = (const float*)d_in[0];
  const float* Wq    = (const float*)d_in[1];
  const float* Wk    = (const float*)d_in[2];
  const float* Wv    = (const float*)d_in[3];
  const float* Wo    = (const float*)d_in[4];
  const float* g1    = (const float*)d_in[5];
  const float* bb1   = (const float*)d_in[6];
  const float* W1    = (const float*)d_in[7];
  const float* bias1 = (const float*)d_in[8];
  const float* W2    = (const float*)d_in[9];
  const float* bias2 = (const float*)d_in[10];
  const float* g2    = (const float*)d_in[11];
  const float* bb2   = (const float*)d_in[12];

  char* ws = (char*)d_ws;
  const size_t MB = 1048576;
  u16* xb     = (u16*)(ws);
  u16* wqkvT  = (u16*)(ws + 8 * MB);
  u16* woT    = (u16*)(ws + 38 * MB);
  u16* qkv    = (u16*)(ws + 40 * MB);
  u16* vT     = (u16*)(ws + 64 * MB);
  u16* ob     = (u16*)(ws + 72 * MB);
  float* aout = (float*)(ws);            // 2 partials, 16MB each
  u16* x1     = (u16*)(ws + 64 * MB);
  float* x1f  = (float*)(ws + 40 * MB);
  u16* w1T    = (u16*)(ws + 56 * MB);
  u16* w2T    = (u16*)(ws);
  u16* hbuf   = (u16*)(ws + 8 * MB);
  float* ffn  = (float*)(ws + 56 * MB);  // 2 partials, 16MB each

  dim3 tb(32, 8, 1);
  cvt_f2b_kernel<<<4096, 256, 0, stream>>>(x, xb);
  transpose_f2b_kernel<<<dim3(2, 32, 16), tb, 0, stream>>>(Wq, wqkvT,           1024, 64, 1024);
  transpose_f2b_kernel<<<dim3(2, 32, 16), tb, 0, stream>>>(Wk, wqkvT + 1048576, 1024, 64, 1024);
  transpose_f2b_kernel<<<dim3(2, 32, 16), tb, 0, stream>>>(Wv, wqkvT + 2097152, 1024, 64, 1024);
  transpose_f2b_kernel<<<dim3(32, 32, 1), tb, 0, stream>>>(Wo, woT, 1024, 1024, 1024);

  // qkv = x @ [Wq|Wk|Wv]  (bf16 out) — BK=32 (768-block grid, tail-friendly)
  gemm_bt<<<dim3(24, 32), 256, 0, stream>>>(xb, wqkvT, nullptr, qkv, 4096, 3072, 1024, 1);
  // vT = (V slice of qkv)^T
  transpose_b2b_kernel<<<dim3(32, 128), tb, 0, stream>>>(qkv + 2048, vT, 3072, 4096);
  // attention -> ob (bf16), single kernel, 32 q/wave
  attn_kernel<<<dim3(16, 16, 2), 256, 0, stream>>>(qkv, vT, ob);
  // aout partials = ob @ Wo  (f32, split-K=2, BK=64, XCD-swizzled)
  gemm_bt_k64<<<dim3(8, 32, 2), 256, 0, stream>>>(ob, woT, nullptr, aout, 4096, 1024, 1024, 0);
  // x1 = LN(aout0 + aout1 + x): bf16 (FFN1 operand) + f32 (LN2 residual)
  ln_kernel<<<4096, 256, 0, stream>>>(aout, aout + 4194304, x, nullptr, g1, bb1, x1, x1f);
  // lazy weight transposes into dead regions
  transpose_f2b_kernel<<<dim3(128, 32, 1), tb, 0, stream>>>(W1, w1T, 1024, 4096, 1024);
  transpose_f2b_kernel<<<dim3(32, 128, 1), tb, 0, stream>>>(W2, w2T, 4096, 1024, 4096);
  // hbuf = relu(x1 @ W1 + b1)  (bf16 out) — BK=64: 32 MFMA/barrier
  gemm_bt_k64<<<dim3(32, 32, 1), 256, 0, stream>>>(x1, w1T, bias1, hbuf, 4096, 4096, 1024, 1 | 2 | 4);
  // ffn partials = hbuf @ W2  (f32, split-K=2, BK=64, XCD-swizzled)
  gemm_bt_k64<<<dim3(8, 32, 2), 256, 0, stream>>>(hbuf, w2T, nullptr, ffn, 4096, 1024, 4096, 0);
  // out = LN(ffn0 + ffn1 + bias2 + x1f) -> f32 d_out
  ln_kernel<<<4096, 256, 0, stream>>>(ffn, ffn + 4194304, x1f, bias2, g2, bb2, nullptr, (float*)d_out);
}